// Round 14
// baseline (165.477 us; speedup 1.0000x reference)
//
#include <hip/hip_runtime.h>
#include <hip/hip_bf16.h>

#define NN 4096

typedef unsigned short u16;
typedef __attribute__((ext_vector_type(8))) short bf16x8;
typedef __attribute__((ext_vector_type(4))) float f32x4;

// fp32 -> bf16 round-to-nearest-even
static __device__ __forceinline__ u16 f2bf(float x) {
  unsigned u = __float_as_uint(x);
  u += 0x7fff + ((u >> 16) & 1);
  return (u16)(u >> 16);
}
static __device__ __forceinline__ float bf2f(u16 h) {
  return __uint_as_float((unsigned)h << 16);
}

// async global->LDS, 16B per lane; LDS dest = wave-uniform base + lane*16
static __device__ __forceinline__ void gload_lds16(const void* g, void* l) {
  __builtin_amdgcn_global_load_lds(
      (const __attribute__((address_space(1))) void*)g,
      (__attribute__((address_space(3))) void*)l, 16, 0, 0);
}

// Balanced partition of the 3264 global K64-steps over 256 blocks:
// blocks 0..191 get 13 steps, 192..255 get 12 (192*13 + 64*12 = 3264).
static __device__ __forceinline__ int stepStart(int b) {
  return b < 192 ? 13 * b : 2496 + 12 * (b - 192);
}
static __device__ __forceinline__ int bOf(int s) {
  return s < 2496 ? s / 13 : 192 + (s - 2496) / 12;
}

// ---------------------------------------------------------------------------
// Pass 1 (fused, grid 3200): same as R12 (proven).
//  [0,1024):    A path: tril bf16 convert (kb<=bi); kb>bi: zero strict-upper
//               C block, and zero super-diagonal Ab block (bi even, kb=bi+1).
//  [1024,3136): B -> Bt transpose (tril bf16), 2112 needed 64x64 tiles.
//  [3136,3200): zero sub-diagonal Bt 128-blocks.
// ---------------------------------------------------------------------------
__global__ __launch_bounds__(256) void convert_fused(
    const float* __restrict__ A, const float* __restrict__ B,
    u16* __restrict__ Ab, u16* __restrict__ Bt, float* __restrict__ C) {
  __shared__ float t[64][65];
  const int blk = blockIdx.x;
  const int tid = threadIdx.x;

  if (blk < 1024) {  // ---- A path ----
    const int kb = blk & 31, bi = blk >> 5;
    const int rr = tid >> 5;
    if (kb > bi) {
      const float4 z = {0.f, 0.f, 0.f, 0.f};
      const int c4 = (tid & 31);
#pragma unroll
      for (int p = 0; p < 16; ++p)
        ((float4*)&C[(long)(bi * 128 + p * 8 + rr) * NN + kb * 128])[c4] = z;
      if (kb == bi + 1 && !(bi & 1)) {  // super-diagonal Ab: real zeros
        const ushort4 zz = {0, 0, 0, 0};
        const int c4b = (tid & 31) * 4;
#pragma unroll
        for (int p = 0; p < 16; ++p)
          *(ushort4*)&Ab[(long)(bi * 128 + p * 8 + rr) * NN + kb * 128 + c4b] =
              zz;
      }
      return;
    }
    const int c4 = (tid & 31) * 4;
    const bool diag = (kb == bi);
#pragma unroll
    for (int p = 0; p < 16; ++p) {
      const int row = p * 8 + rr;
      const long off = (long)(bi * 128 + row) * NN + kb * 128 + c4;
      float4 v = *(const float4*)&A[off];
      ushort4 o;
      if (diag) {
        const int i = bi * 128 + row, k = kb * 128 + c4;
        o.x = (k + 0 <= i) ? f2bf(v.x) : (u16)0;
        o.y = (k + 1 <= i) ? f2bf(v.y) : (u16)0;
        o.z = (k + 2 <= i) ? f2bf(v.z) : (u16)0;
        o.w = (k + 3 <= i) ? f2bf(v.w) : (u16)0;
      } else {
        o.x = f2bf(v.x); o.y = f2bf(v.y); o.z = f2bf(v.z); o.w = f2bf(v.w);
      }
      *(ushort4*)&Ab[off] = o;
    }
    return;
  }

  if (blk >= 3136) {  // ---- sub-diagonal Bt zero blocks ----
    const int idx = blk - 3136;  // 0..63
    const int q = idx >> 2;
    const int n0 = (2 * (2 * q + 1) + (idx & 1)) * 64;
    const int k0 = (2 * (2 * q) + ((idx >> 1) & 1)) * 64;
    const int n = tid >> 3;
    const int kc = (tid & 7) * 8;
    const uint4 z = {0u, 0u, 0u, 0u};
#pragma unroll
    for (int p = 0; p < 2; ++p)
      *(uint4*)&Bt[(long)(n0 + n + p * 32) * NN + k0 + kc] = z;
    return;
  }

  // ---- B path: pair-decoded 64x64 transpose tile ----
  const int t4 = blk - 1024;  // 0..2111
  int prem = t4 >> 2, N = 0;
  while (prem >= 32 - N) { prem -= 32 - N; ++N; }
  const int K = N + prem;  // N <= K
  const int sub = t4 & 3;
  const int n0 = (2 * N + (sub & 1)) * 64;
  const int k0 = (2 * K + (sub >> 1)) * 64;

  if (n0 > k0 + 63) {  // fully above diagonal -> zeros
    const int n = tid >> 3;
    const int kc = (tid & 7) * 8;
    const uint4 z = {0u, 0u, 0u, 0u};
#pragma unroll
    for (int p = 0; p < 2; ++p)
      *(uint4*)&Bt[(long)(n0 + n + p * 32) * NN + k0 + kc] = z;
    return;
  }

#pragma unroll
  for (int p = 0; p < 4; ++p) {
    const int r = (tid >> 4) + p * 16;
    const int c = (tid & 15) * 4;
    float4 v = *(const float4*)&B[(long)(k0 + r) * NN + n0 + c];
    const int kg = k0 + r;
    t[r][c + 0] = (n0 + c + 0 <= kg) ? v.x : 0.f;
    t[r][c + 1] = (n0 + c + 1 <= kg) ? v.y : 0.f;
    t[r][c + 2] = (n0 + c + 2 <= kg) ? v.z : 0.f;
    t[r][c + 3] = (n0 + c + 3 <= kg) ? v.w : 0.f;
  }
  __syncthreads();

#pragma unroll
  for (int p = 0; p < 2; ++p) {
    const int n = (tid >> 3) + p * 32;
    const int kc = (tid & 7) * 8;
    union { u16 h[8]; uint4 v; } pk;
#pragma unroll
    for (int j = 0; j < 8; ++j) pk.h[j] = f2bf(t[kc + j][n]);
    *(uint4*)&Bt[(long)(n0 + n) * NN + k0 + kc] = pk.v;
  }
}

// ---------------------------------------------------------------------------
// Pass 2: BALANCED PERSISTENT 8-phase tril GEMM. Exactly 256 blocks (1/CU,
// zero dispatch tail); tiles (256x256, longest-K-first) are laid out in one
// global K64-step sequence [0,3264); block b owns steps
// [stepStart(b), stepStart(b+1)) -- 12/13 steps each, perfectly balanced.
// A block walks its slice segment-by-segment: segment with k0==0 is the
// tile's OWNER (writes C, diag-masked); a block's FIRST segment may start
// mid-tile (continuation) -> writes bf16 slab P[blockIdx] (each block has
// at most one continuation => trivial slab indexing, 256 slabs = 32 MB).
// Inner schedule = R12 (proven): 128 KB dbuf LDS, counted vmcnt(8), 4
// phases {ds_read; barrier; lgkmcnt(0)+sched_barrier; setprio(1) 16 MFMA;
// barrier}; T2 zero-conflict swizzle.
// ---------------------------------------------------------------------------
__global__ __launch_bounds__(512, 2) void gemm_tril(
    const u16* __restrict__ Ab, const u16* __restrict__ Bt,
    float* __restrict__ C, u16* __restrict__ P) {
  extern __shared__ u16 lds[];  // [2][16384] A | [2][16384] B = 128 KB
  u16* AsB = lds;
  u16* BsB = lds + 32768;

  const int tid = threadIdx.x;
  const int lane = tid & 63;
  const int wid = tid >> 6;  // 0..7
  const int wm = wid >> 2;   // 0..1 (128-row half)
  const int wn = wid & 3;    // 0..3 (64-col block)
  const int sm = lane >> 3;
  const int sks = ((lane & 7) ^ sm) * 8;  // pre-swizzled source col (u16)
  const int rsel = lane & 7;

  int s0 = stepStart(blockIdx.x);
  const int s1 = stepStart(blockIdx.x + 1);

  // ---- locate tile containing s0 (tiles: bi=15..0, bj=0..bi) ----
  int S = 0, bi = 15;
  for (;;) {
    const int rl = 2 * (bi + 1) * (bi + 2);  // row bi total K64-steps
    if (s0 < S + rl) break;
    S += rl;
    --bi;
  }
  int bj = 0;
  while (s0 >= S + 4 * (bi - bj + 1)) {
    S += 4 * (bi - bj + 1);
    ++bj;
  }

  while (s0 < s1) {
    const int L = 4 * (bi - bj + 1);
    const int k0s = s0 - S;
    const int nk = min(L - k0s, s1 - s0);
    const int rA = bi * 256;
    const int rB = bj * 256;
    const long kbase = (long)bj * 256 + (long)k0s * 64;

    f32x4 acc[8][4];
#pragma unroll
    for (int i = 0; i < 8; ++i)
#pragma unroll
      for (int j = 0; j < 4; ++j) acc[i][j] = (f32x4){0.f, 0.f, 0.f, 0.f};

#define STAGE(kt, b)                                                       \
  do {                                                                     \
    const long k0 = kbase + (long)(kt)*64;                                 \
    _Pragma("unroll") for (int c = 0; c < 4; ++c) {                        \
      const int ch = wid * 4 + c;                                          \
      gload_lds16(Ab + ((long)(rA + ch * 8 + sm) * NN + k0 + sks),         \
                  AsB + (b)*16384 + ch * 512);                             \
      gload_lds16(Bt + ((long)(rB + ch * 8 + sm) * NN + k0 + sks),         \
                  BsB + (b)*16384 + ch * 512);                             \
    }                                                                      \
  } while (0)

    STAGE(0, 0);

    for (int kt = 0; kt < nk; ++kt) {
      const int cur = kt & 1;
      if (kt + 1 < nk) {
        STAGE(kt + 1, cur ^ 1);  // loads stay in flight across barriers
        asm volatile("s_waitcnt vmcnt(8)" ::: "memory");  // cur's 8 landed
      } else {
        asm volatile("s_waitcnt vmcnt(0)" ::: "memory");
      }
      __builtin_amdgcn_s_barrier();  // buf[cur] staged by all waves

      const u16* As = AsB + cur * 16384;
      const u16* Bs = BsB + cur * 16384;

      bf16x8 bb[4][2];
#pragma unroll
      for (int p = 0; p < 4; ++p) {  // phase p: m-reps {2p, 2p+1}
        bf16x8 aa[2][2];
#pragma unroll
        for (int mm = 0; mm < 2; ++mm)
#pragma unroll
          for (int kk = 0; kk < 2; ++kk) {
            const int fr = wm * 128 + (2 * p + mm) * 16 + (lane & 15);
            const int slot = ((kk * 4 + (lane >> 4)) ^ rsel) * 8;
            aa[mm][kk] = *(const bf16x8*)&As[fr * 64 + slot];
          }
        if (p == 0) {
#pragma unroll
          for (int n4 = 0; n4 < 4; ++n4)
#pragma unroll
            for (int kk = 0; kk < 2; ++kk) {
              const int fr = wn * 64 + n4 * 16 + (lane & 15);
              const int slot = ((kk * 4 + (lane >> 4)) ^ rsel) * 8;
              bb[n4][kk] = *(const bf16x8*)&Bs[fr * 64 + slot];
            }
        }
        __builtin_amdgcn_s_barrier();
        asm volatile("s_waitcnt lgkmcnt(0)" ::: "memory");
        __builtin_amdgcn_sched_barrier(0);
        __builtin_amdgcn_s_setprio(1);
#pragma unroll
        for (int kk = 0; kk < 2; ++kk)
#pragma unroll
          for (int mm = 0; mm < 2; ++mm)
#pragma unroll
            for (int n4 = 0; n4 < 4; ++n4)
              acc[2 * p + mm][n4] = __builtin_amdgcn_mfma_f32_16x16x32_bf16(
                  aa[mm][kk], bb[n4][kk], acc[2 * p + mm][n4], 0, 0, 0);
        __builtin_amdgcn_s_setprio(0);
        __builtin_amdgcn_s_barrier();  // phase-end; also guards next STAGE
      }
    }
#undef STAGE

    // ---- segment epilogue: C/D layout col=lane&15, row=(lane>>4)*4+r ----
    const int lrow = wm * 128 + (lane >> 4) * 4;
    const int lcol = wn * 64 + (lane & 15);
    if (k0s == 0) {  // owner of this tile
      const bool diag = (bi == bj);
#pragma unroll
      for (int m4 = 0; m4 < 8; ++m4)
#pragma unroll
        for (int n4 = 0; n4 < 4; ++n4)
#pragma unroll
          for (int r = 0; r < 4; ++r) {
            const int gi = rA + lrow + m4 * 16 + r;
            const int gj = rB + lcol + n4 * 16;
            float v = acc[m4][n4][r];
            if (diag && gj > gi) v = 0.f;
            C[(long)gi * NN + gj] = v;
          }
    } else {  // continuation (only possible for a block's first segment)
      u16* slab = P + (long)blockIdx.x * 65536;  // 256x256 bf16
#pragma unroll
      for (int m4 = 0; m4 < 8; ++m4)
#pragma unroll
        for (int n4 = 0; n4 < 4; ++n4)
#pragma unroll
          for (int r = 0; r < 4; ++r)
            slab[(lrow + m4 * 16 + r) * 256 + lcol + n4 * 16] =
                f2bf(acc[m4][n4][r]);
    }

    s0 += nk;
    S += L;
    if (++bj > bi) { --bi; bj = 0; }
  }
}

// ---------------------------------------------------------------------------
// Pass 3: for each split tile, add the continuation slabs (blocks b0+1..
// blast) into C. Grid = 136 tiles x 4 row-stripes.
// ---------------------------------------------------------------------------
__global__ __launch_bounds__(256) void reduce_partials(
    float* __restrict__ C, const u16* __restrict__ P) {
  const int T = blockIdx.x >> 2;
  const int stripe = blockIdx.x & 3;

  // decode tile index T -> (bi, bj) and global step prefix S
  int rem = T, bi = 15, S = 0;
  while (rem > bi) {
    rem -= bi + 1;
    S += 2 * (bi + 1) * (bi + 2);
    --bi;
  }
  const int bj = rem;
  for (int j = 0; j < bj; ++j) S += 4 * (bi - j + 1);
  const int L = 4 * (bi - bj + 1);

  const int b0 = bOf(S);
  const int blast = bOf(S + L - 1);
  if (blast == b0) return;  // tile not split

  const int tid = threadIdx.x;
#pragma unroll
  for (int p = 0; p < 16; ++p) {
    const int idx = p * 256 + tid;  // 4096 float4 per 64-row stripe
    const int row = stripe * 64 + (idx >> 6);
    const int col = (idx & 63) * 4;
    const long coff = (long)(bi * 256 + row) * NN + bj * 256 + col;
    float4 acc = *(const float4*)&C[coff];
    for (int e = b0 + 1; e <= blast; ++e) {
      const ushort4 q =
          *(const ushort4*)&P[(long)e * 65536 + row * 256 + col];
      acc.x += bf2f(q.x); acc.y += bf2f(q.y);
      acc.z += bf2f(q.z); acc.w += bf2f(q.w);
    }
    *(float4*)&C[coff] = acc;
  }
}

// ---------------------------------------------------------------------------
// Fallback (ws too small): naive fp32.
// ---------------------------------------------------------------------------
__global__ void naive_tril(const float* __restrict__ A,
                           const float* __restrict__ B, float* __restrict__ C) {
  const int j = blockIdx.x * 256 + threadIdx.x;
  const int i = blockIdx.y;
  float s = 0.f;
  for (int k = j; k <= i; ++k) s += A[(long)i * NN + k] * B[(long)k * NN + j];
  C[(long)i * NN + j] = s;
}

extern "C" void kernel_launch(void* const* d_in, const int* in_sizes, int n_in,
                              void* d_out, int out_size, void* d_ws,
                              size_t ws_size, hipStream_t stream) {
  const float* A = (const float*)d_in[0];
  const float* B = (const float*)d_in[1];
  float* C = (float*)d_out;

  const size_t opbytes = (size_t)2 * NN * NN * sizeof(u16);     // 64 MB
  const size_t need = opbytes + (size_t)256 * 131072;           // +32 MB slabs

  if (ws_size < need) {
    naive_tril<<<dim3(16, NN), 256, 0, stream>>>(A, B, C);
    return;
  }

  u16* Ab = (u16*)d_ws;
  u16* Bt = Ab + (long)NN * NN;
  u16* P = (u16*)((char*)d_ws + opbytes);

  hipFuncSetAttribute((const void*)gemm_tril,
                      hipFuncAttributeMaxDynamicSharedMemorySize, 131072);

  convert_fused<<<3200, 256, 0, stream>>>(A, B, Ab, Bt, C);
  gemm_tril<<<256, 512, 131072, stream>>>(Ab, Bt, C, P);
  reduce_partials<<<544, 256, 0, stream>>>(C, P);
}

// Round 15
// 80.579 us; speedup vs baseline: 2.0536x; 2.0536x over previous
//
#include <hip/hip_runtime.h>
#include <hip/hip_bf16.h>

#define NN 4096

typedef unsigned short u16;
typedef __attribute__((ext_vector_type(8))) short bf16x8;
typedef __attribute__((ext_vector_type(4))) float f32x4;

// fp32 -> bf16 round-to-nearest-even
static __device__ __forceinline__ u16 f2bf(float x) {
  unsigned u = __float_as_uint(x);
  u += 0x7fff + ((u >> 16) & 1);
  return (u16)(u >> 16);
}
static __device__ __forceinline__ float bf2f(u16 h) {
  return __uint_as_float((unsigned)h << 16);
}

// async global->LDS, 16B per lane; LDS dest = wave-uniform base + lane*16
static __device__ __forceinline__ void gload_lds16(const void* g, void* l) {
  __builtin_amdgcn_global_load_lds(
      (const __attribute__((address_space(1))) void*)g,
      (__attribute__((address_space(3))) void*)l, 16, 0, 0);
}

// F(M) = sum_{j=0}^{M-1} floor(j/2^lg)
static __device__ __forceinline__ int Fpre(int M, int lg) {
  if (M <= 0) return 0;
  const int q = (M - 1) >> lg, r = (M - 1) & ((1 << lg) - 1);
  return ((q * (q - 1)) << (lg - 1)) + q * (r + 1);
}

// ---------------------------------------------------------------------------
// Pass 1 (fused, grid 3200): identical to R12 (proven).
// ---------------------------------------------------------------------------
__global__ __launch_bounds__(256) void convert_fused(
    const float* __restrict__ A, const float* __restrict__ B,
    u16* __restrict__ Ab, u16* __restrict__ Bt, float* __restrict__ C) {
  __shared__ float t[64][65];
  const int blk = blockIdx.x;
  const int tid = threadIdx.x;

  if (blk < 1024) {  // ---- A path ----
    const int kb = blk & 31, bi = blk >> 5;
    const int rr = tid >> 5;
    if (kb > bi) {
      const float4 z = {0.f, 0.f, 0.f, 0.f};
      const int c4 = (tid & 31);
#pragma unroll
      for (int p = 0; p < 16; ++p)
        ((float4*)&C[(long)(bi * 128 + p * 8 + rr) * NN + kb * 128])[c4] = z;
      if (kb == bi + 1 && !(bi & 1)) {  // super-diagonal Ab: real zeros
        const ushort4 zz = {0, 0, 0, 0};
        const int c4b = (tid & 31) * 4;
#pragma unroll
        for (int p = 0; p < 16; ++p)
          *(ushort4*)&Ab[(long)(bi * 128 + p * 8 + rr) * NN + kb * 128 + c4b] =
              zz;
      }
      return;
    }
    const int c4 = (tid & 31) * 4;
    const bool diag = (kb == bi);
#pragma unroll
    for (int p = 0; p < 16; ++p) {
      const int row = p * 8 + rr;
      const long off = (long)(bi * 128 + row) * NN + kb * 128 + c4;
      float4 v = *(const float4*)&A[off];
      ushort4 o;
      if (diag) {
        const int i = bi * 128 + row, k = kb * 128 + c4;
        o.x = (k + 0 <= i) ? f2bf(v.x) : (u16)0;
        o.y = (k + 1 <= i) ? f2bf(v.y) : (u16)0;
        o.z = (k + 2 <= i) ? f2bf(v.z) : (u16)0;
        o.w = (k + 3 <= i) ? f2bf(v.w) : (u16)0;
      } else {
        o.x = f2bf(v.x); o.y = f2bf(v.y); o.z = f2bf(v.z); o.w = f2bf(v.w);
      }
      *(ushort4*)&Ab[off] = o;
    }
    return;
  }

  if (blk >= 3136) {  // ---- sub-diagonal Bt zero blocks ----
    const int idx = blk - 3136;  // 0..63
    const int q = idx >> 2;
    const int n0 = (2 * (2 * q + 1) + (idx & 1)) * 64;
    const int k0 = (2 * (2 * q) + ((idx >> 1) & 1)) * 64;
    const int n = tid >> 3;
    const int kc = (tid & 7) * 8;
    const uint4 z = {0u, 0u, 0u, 0u};
#pragma unroll
    for (int p = 0; p < 2; ++p)
      *(uint4*)&Bt[(long)(n0 + n + p * 32) * NN + k0 + kc] = z;
    return;
  }

  // ---- B path: pair-decoded 64x64 transpose tile ----
  const int t4 = blk - 1024;  // 0..2111
  int prem = t4 >> 2, N = 0;
  while (prem >= 32 - N) { prem -= 32 - N; ++N; }
  const int K = N + prem;  // N <= K
  const int sub = t4 & 3;
  const int n0 = (2 * N + (sub & 1)) * 64;
  const int k0 = (2 * K + (sub >> 1)) * 64;

  if (n0 > k0 + 63) {  // fully above diagonal -> zeros
    const int n = tid >> 3;
    const int kc = (tid & 7) * 8;
    const uint4 z = {0u, 0u, 0u, 0u};
#pragma unroll
    for (int p = 0; p < 2; ++p)
      *(uint4*)&Bt[(long)(n0 + n + p * 32) * NN + k0 + kc] = z;
    return;
  }

#pragma unroll
  for (int p = 0; p < 4; ++p) {
    const int r = (tid >> 4) + p * 16;
    const int c = (tid & 15) * 4;
    float4 v = *(const float4*)&B[(long)(k0 + r) * NN + n0 + c];
    const int kg = k0 + r;
    t[r][c + 0] = (n0 + c + 0 <= kg) ? v.x : 0.f;
    t[r][c + 1] = (n0 + c + 1 <= kg) ? v.y : 0.f;
    t[r][c + 2] = (n0 + c + 2 <= kg) ? v.z : 0.f;
    t[r][c + 3] = (n0 + c + 3 <= kg) ? v.w : 0.f;
  }
  __syncthreads();

#pragma unroll
  for (int p = 0; p < 2; ++p) {
    const int n = (tid >> 3) + p * 32;
    const int kc = (tid & 7) * 8;
    union { u16 h[8]; uint4 v; } pk;
#pragma unroll
    for (int j = 0; j < 8; ++j) pk.h[j] = f2bf(t[kc + j][n]);
    *(uint4*)&Bt[(long)(n0 + n) * NN + k0 + kc] = pk.v;
  }
}

// ---------------------------------------------------------------------------
// Pass 2: R12 structure (260-item static grid, 256x256 tile, 128 KB dbuf,
// T2 swizzle) with a LEANER STEP SCHEDULE:
//  - ONE barrier per K64-step (intra-step phases only read LDS; the write
//    hazard exists only at step boundaries).
//  - ds_reads pipelined one phase ahead with counted lgkmcnt(4): B frags +
//    phase-0 A frags at step start; phase p issues phase p+1's A frags,
//    waits for current frags only, MFMAs under setprio.
//  - STAGE for step t+1 spread 2 loads/phase (fine interleave, m201).
//  - bf16 partial slabs (halves reduce traffic; absmax margin proven R13).
// ---------------------------------------------------------------------------
__global__ __launch_bounds__(512, 2) void gemm_tril(
    const u16* __restrict__ Ab, const u16* __restrict__ Bt,
    float* __restrict__ C, u16* __restrict__ P, int lg) {
  extern __shared__ u16 lds[];  // [2][16384] A | [2][16384] B = 128 KB
  u16* AsB = lds;
  u16* BsB = lds + 32768;

  const int tid = threadIdx.x;
  const int lane = tid & 63;
  const int wid = tid >> 6;  // 0..7
  const int wm = wid >> 2;   // 0..1 (128-row half)
  const int wn = wid & 3;    // 0..3 (64-col block)
  const int sm = lane >> 3;
  const int sks = ((lane & 7) ^ sm) * 8;  // pre-swizzled source col (u16)
  const int rsel = lane & 7;

  // ---- decode blockIdx.x -> (bi, bj, chunk); 256-rows longest-K-first ----
  int rem = blockIdx.x, bi = 15, slabpre = 0;
  for (int s = 0; s < 16; ++s) {
    bi = 15 - s;
    const int fp = Fpre(bi + 1, lg);
    const int g = (bi + 1) + fp;
    if (rem < g) break;
    rem -= g;
    slabpre += fp;
  }
  int bj = 0;
  for (;;) {
    const int c = ((bi - bj) >> lg) + 1;  // chunks of tile (bi,bj)
    if (rem < c) break;
    rem -= c;
    ++bj;
  }
  const int chunk = rem;
  const int L64 = 4 * (bi - bj + 1);
  const int H64 = 4 << lg;
  const int start = chunk * H64;
  const int nk = min(H64, L64 - start);
  const int rA = bi * 256;
  const int rB = bj * 256;
  const long kbase = (long)bj * 256 + (long)start * 64;

  f32x4 acc[8][4];
#pragma unroll
  for (int i = 0; i < 8; ++i)
#pragma unroll
    for (int j = 0; j < 4; ++j) acc[i][j] = (f32x4){0.f, 0.f, 0.f, 0.f};

  // stage part c (of 4) of K64-step kt into buffer b: 2 gload_lds16
#define STAGE_PART(kt, b, c)                                               \
  do {                                                                     \
    const long k0 = kbase + (long)(kt)*64;                                 \
    const int ch = wid * 4 + (c);                                          \
    gload_lds16(Ab + ((long)(rA + ch * 8 + sm) * NN + k0 + sks),           \
                AsB + (b)*16384 + ch * 512);                               \
    gload_lds16(Bt + ((long)(rB + ch * 8 + sm) * NN + k0 + sks),           \
                BsB + (b)*16384 + ch * 512);                               \
  } while (0)

#pragma unroll
  for (int c = 0; c < 4; ++c) STAGE_PART(0, 0, c);

  for (int kt = 0; kt < nk; ++kt) {
    const int cur = kt & 1;
    asm volatile("s_waitcnt vmcnt(0)" ::: "memory");  // own stage landed
    __builtin_amdgcn_s_barrier();                     // all waves' stage done
    __builtin_amdgcn_sched_barrier(0);                // no read hoists above

    const u16* As = AsB + cur * 16384;
    const u16* Bs = BsB + cur * 16384;
    const bool pf = (kt + 1 < nk);

    // B fragments (whole step) + A fragments for phase 0
    bf16x8 bb[4][2];
#pragma unroll
    for (int n4 = 0; n4 < 4; ++n4)
#pragma unroll
      for (int kk = 0; kk < 2; ++kk) {
        const int fr = wn * 64 + n4 * 16 + (lane & 15);
        const int slot = ((kk * 4 + (lane >> 4)) ^ rsel) * 8;
        bb[n4][kk] = *(const bf16x8*)&Bs[fr * 64 + slot];
      }
    bf16x8 aa[2][2][2];  // [phase&1][mm][kk]
#pragma unroll
    for (int mm = 0; mm < 2; ++mm)
#pragma unroll
      for (int kk = 0; kk < 2; ++kk) {
        const int fr = wm * 128 + mm * 16 + (lane & 15);
        const int slot = ((kk * 4 + (lane >> 4)) ^ rsel) * 8;
        aa[0][mm][kk] = *(const bf16x8*)&As[fr * 64 + slot];
      }

#pragma unroll
    for (int p = 0; p < 4; ++p) {
      if (pf) STAGE_PART(kt + 1, cur ^ 1, p);  // 2 global loads interleaved
      if (p < 3) {  // prefetch next phase's A fragments
#pragma unroll
        for (int mm = 0; mm < 2; ++mm)
#pragma unroll
          for (int kk = 0; kk < 2; ++kk) {
            const int fr = wm * 128 + (2 * (p + 1) + mm) * 16 + (lane & 15);
            const int slot = ((kk * 4 + (lane >> 4)) ^ rsel) * 8;
            aa[(p + 1) & 1][mm][kk] = *(const bf16x8*)&As[fr * 64 + slot];
          }
        asm volatile("s_waitcnt lgkmcnt(4)" ::: "memory");  // cur frags done
      } else {
        asm volatile("s_waitcnt lgkmcnt(0)" ::: "memory");
      }
      __builtin_amdgcn_sched_barrier(0);  // rule #18: no MFMA hoist past wait
      __builtin_amdgcn_s_setprio(1);
#pragma unroll
      for (int kk = 0; kk < 2; ++kk)
#pragma unroll
        for (int mm = 0; mm < 2; ++mm)
#pragma unroll
          for (int n4 = 0; n4 < 4; ++n4)
            acc[2 * p + mm][n4] = __builtin_amdgcn_mfma_f32_16x16x32_bf16(
                aa[p & 1][mm][kk], bb[n4][kk], acc[2 * p + mm][n4], 0, 0, 0);
      __builtin_amdgcn_s_setprio(0);
    }
  }
#undef STAGE_PART

  // ---- epilogue: C/D layout col=lane&15, row=(lane>>4)*4+r ----
  const int lrow = wm * 128 + (lane >> 4) * 4;
  const int lcol = wn * 64 + (lane & 15);
  if (chunk == 0) {
    const bool diag = (bi == bj);
#pragma unroll
    for (int m4 = 0; m4 < 8; ++m4)
#pragma unroll
      for (int n4 = 0; n4 < 4; ++n4)
#pragma unroll
        for (int r = 0; r < 4; ++r) {
          const int gi = rA + lrow + m4 * 16 + r;
          const int gj = rB + lcol + n4 * 16;
          float v = acc[m4][n4][r];
          if (diag && gj > gi) v = 0.f;
          C[(long)gi * NN + gj] = v;
        }
  } else {
    const int slabidx =
        slabpre + (Fpre(bi + 1, lg) - Fpre(bi - bj + 1, lg)) + (chunk - 1);
    u16* slab = P + (long)slabidx * 65536;  // 256x256 bf16 = 128 KB
#pragma unroll
    for (int m4 = 0; m4 < 8; ++m4)
#pragma unroll
      for (int n4 = 0; n4 < 4; ++n4)
#pragma unroll
        for (int r = 0; r < 4; ++r)
          slab[(lrow + m4 * 16 + r) * 256 + lcol + n4 * 16] =
              f2bf(acc[m4][n4][r]);
  }
}

// ---------------------------------------------------------------------------
// Pass 3: add bf16 partial slabs into C. Multi-chunk tiles only
// (bi-bj >= 2^lg), 4 row-stripes per tile.
// ---------------------------------------------------------------------------
__global__ __launch_bounds__(256) void reduce_partials(
    float* __restrict__ C, const u16* __restrict__ P, int lg) {
  const int G = 1 << lg;
  const int tb = blockIdx.x >> 2;
  const int stripe = blockIdx.x & 3;
  int rem = tb, bi = 15, slabpre = 0;
  for (int s = 0; s < 16; ++s) {
    bi = 15 - s;
    const int g = (bi + 1 - G > 0) ? bi + 1 - G : 0;
    if (rem < g) break;
    rem -= g;
    slabpre += Fpre(bi + 1, lg);
  }
  const int bj = rem;  // bj <= bi-G -> nch >= 2
  const int nch = ((bi - bj) >> lg) + 1;
  const int slaboff = slabpre + (Fpre(bi + 1, lg) - Fpre(bi - bj + 1, lg));

  const int tid = threadIdx.x;
#pragma unroll
  for (int p = 0; p < 16; ++p) {
    const int idx = p * 256 + tid;  // 4096 float4 per 64-row stripe
    const int row = stripe * 64 + (idx >> 6);
    const int col = (idx & 63) * 4;
    const long coff = (long)(bi * 256 + row) * NN + bj * 256 + col;
    float4 acc = *(const float4*)&C[coff];
    for (int e = 0; e < nch - 1; ++e) {
      const ushort4 q =
          *(const ushort4*)&P[(long)(slaboff + e) * 65536 + row * 256 + col];
      acc.x += bf2f(q.x); acc.y += bf2f(q.y);
      acc.z += bf2f(q.z); acc.w += bf2f(q.w);
    }
    *(float4*)&C[coff] = acc;
  }
}

// ---------------------------------------------------------------------------
// Fallback (ws too small): naive fp32.
// ---------------------------------------------------------------------------
__global__ void naive_tril(const float* __restrict__ A,
                           const float* __restrict__ B, float* __restrict__ C) {
  const int j = blockIdx.x * 256 + threadIdx.x;
  const int i = blockIdx.y;
  float s = 0.f;
  for (int k = j; k <= i; ++k) s += A[(long)i * NN + k] * B[(long)k * NN + j];
  C[(long)i * NN + j] = s;
}

extern "C" void kernel_launch(void* const* d_in, const int* in_sizes, int n_in,
                              void* d_out, int out_size, void* d_ws,
                              size_t ws_size, hipStream_t stream) {
  const float* A = (const float*)d_in[0];
  const float* B = (const float*)d_in[1];
  float* C = (float*)d_out;

  const size_t opbytes = (size_t)2 * NN * NN * sizeof(u16);  // 64 MB operands
  const size_t slab = 131072;  // 256x256 bf16
  // tiers (chunk = 4<<lg K64-steps): lg=2 (K=1024) proven best (R12 vs R13)
  const size_t need2 = opbytes + 124 * slab;  // 79.5 MB
  const size_t need3 = opbytes + 36 * slab;

  if (ws_size < opbytes) {
    naive_tril<<<dim3(16, NN), 256, 0, stream>>>(A, B, C);
    return;
  }

  int lg, nitems, nred;
  if (ws_size >= need2)      { lg = 2; nitems = 260; nred = 78; }
  else if (ws_size >= need3) { lg = 3; nitems = 172; nred = 36; }
  else                       { lg = 4; nitems = 136; nred = 0; }

  u16* Ab = (u16*)d_ws;
  u16* Bt = Ab + (long)NN * NN;
  u16* P = (u16*)((char*)d_ws + opbytes);

  hipFuncSetAttribute((const void*)gemm_tril,
                      hipFuncAttributeMaxDynamicSharedMemorySize, 131072);

  convert_fused<<<3200, 256, 0, stream>>>(A, B, Ab, Bt, C);
  gemm_tril<<<nitems, 512, 131072, stream>>>(Ab, Bt, C, P, lg);
  if (nred > 0) reduce_partials<<<nred * 4, 256, 0, stream>>>(C, P, lg);
}

// Round 16
// 79.485 us; speedup vs baseline: 2.0819x; 1.0138x over previous
//
#include <hip/hip_runtime.h>
#include <hip/hip_bf16.h>

#define NN 4096

typedef unsigned short u16;
typedef __attribute__((ext_vector_type(8))) short bf16x8;
typedef __attribute__((ext_vector_type(4))) float f32x4;

// fp32 -> bf16 round-to-nearest-even
static __device__ __forceinline__ u16 f2bf(float x) {
  unsigned u = __float_as_uint(x);
  u += 0x7fff + ((u >> 16) & 1);
  return (u16)(u >> 16);
}
static __device__ __forceinline__ float bf2f(u16 h) {
  return __uint_as_float((unsigned)h << 16);
}

// async global->LDS, 16B per lane; LDS dest = wave-uniform base + lane*16
static __device__ __forceinline__ void gload_lds16(const void* g, void* l) {
  __builtin_amdgcn_global_load_lds(
      (const __attribute__((address_space(1))) void*)g,
      (__attribute__((address_space(3))) void*)l, 16, 0, 0);
}

// F(M) = sum_{j=0}^{M-1} floor(j/2^lg)
static __device__ __forceinline__ int Fpre(int M, int lg) {
  if (M <= 0) return 0;
  const int q = (M - 1) >> lg, r = (M - 1) & ((1 << lg) - 1);
  return ((q * (q - 1)) << (lg - 1)) + q * (r + 1);
}

// ---------------------------------------------------------------------------
// Pass 1 (fused, grid 3200): R12 structure MINUS the strict-upper C zeroing
// (moved to gemm tail items -- convert was half the runtime and its largest
// removable term was the 31 MB of C zero-writes).
//  [0,1024):    A path: tril bf16 convert (kb<=bi); kb==bi+1 & bi even:
//               zero super-diagonal Ab block; other kb>bi: no-op.
//  [1024,3136): B -> Bt transpose (tril bf16), 2112 needed 64x64 tiles.
//  [3136,3200): zero sub-diagonal Bt 128-blocks.
// ---------------------------------------------------------------------------
__global__ __launch_bounds__(256) void convert_fused(
    const float* __restrict__ A, const float* __restrict__ B,
    u16* __restrict__ Ab, u16* __restrict__ Bt) {
  __shared__ float t[64][65];
  const int blk = blockIdx.x;
  const int tid = threadIdx.x;

  if (blk < 1024) {  // ---- A path ----
    const int kb = blk & 31, bi = blk >> 5;
    const int rr = tid >> 5;
    if (kb > bi) {
      if (kb == bi + 1 && !(bi & 1)) {  // super-diagonal Ab: real zeros
        const ushort4 zz = {0, 0, 0, 0};
        const int c4b = (tid & 31) * 4;
#pragma unroll
        for (int p = 0; p < 16; ++p)
          *(ushort4*)&Ab[(long)(bi * 128 + p * 8 + rr) * NN + kb * 128 + c4b] =
              zz;
      }
      return;
    }
    const int c4 = (tid & 31) * 4;
    const bool diag = (kb == bi);
#pragma unroll
    for (int p = 0; p < 16; ++p) {
      const int row = p * 8 + rr;
      const long off = (long)(bi * 128 + row) * NN + kb * 128 + c4;
      float4 v = *(const float4*)&A[off];
      ushort4 o;
      if (diag) {
        const int i = bi * 128 + row, k = kb * 128 + c4;
        o.x = (k + 0 <= i) ? f2bf(v.x) : (u16)0;
        o.y = (k + 1 <= i) ? f2bf(v.y) : (u16)0;
        o.z = (k + 2 <= i) ? f2bf(v.z) : (u16)0;
        o.w = (k + 3 <= i) ? f2bf(v.w) : (u16)0;
      } else {
        o.x = f2bf(v.x); o.y = f2bf(v.y); o.z = f2bf(v.z); o.w = f2bf(v.w);
      }
      *(ushort4*)&Ab[off] = o;
    }
    return;
  }

  if (blk >= 3136) {  // ---- sub-diagonal Bt zero blocks ----
    const int idx = blk - 3136;  // 0..63
    const int q = idx >> 2;
    const int n0 = (2 * (2 * q + 1) + (idx & 1)) * 64;
    const int k0 = (2 * (2 * q) + ((idx >> 1) & 1)) * 64;
    const int n = tid >> 3;
    const int kc = (tid & 7) * 8;
    const uint4 z = {0u, 0u, 0u, 0u};
#pragma unroll
    for (int p = 0; p < 2; ++p)
      *(uint4*)&Bt[(long)(n0 + n + p * 32) * NN + k0 + kc] = z;
    return;
  }

  // ---- B path: pair-decoded 64x64 transpose tile ----
  const int t4 = blk - 1024;  // 0..2111
  int prem = t4 >> 2, N = 0;
  while (prem >= 32 - N) { prem -= 32 - N; ++N; }
  const int K = N + prem;  // N <= K
  const int sub = t4 & 3;
  const int n0 = (2 * N + (sub & 1)) * 64;
  const int k0 = (2 * K + (sub >> 1)) * 64;

  if (n0 > k0 + 63) {  // fully above diagonal -> zeros
    const int n = tid >> 3;
    const int kc = (tid & 7) * 8;
    const uint4 z = {0u, 0u, 0u, 0u};
#pragma unroll
    for (int p = 0; p < 2; ++p)
      *(uint4*)&Bt[(long)(n0 + n + p * 32) * NN + k0 + kc] = z;
    return;
  }

#pragma unroll
  for (int p = 0; p < 4; ++p) {
    const int r = (tid >> 4) + p * 16;
    const int c = (tid & 15) * 4;
    float4 v = *(const float4*)&B[(long)(k0 + r) * NN + n0 + c];
    const int kg = k0 + r;
    t[r][c + 0] = (n0 + c + 0 <= kg) ? v.x : 0.f;
    t[r][c + 1] = (n0 + c + 1 <= kg) ? v.y : 0.f;
    t[r][c + 2] = (n0 + c + 2 <= kg) ? v.z : 0.f;
    t[r][c + 3] = (n0 + c + 3 <= kg) ? v.w : 0.f;
  }
  __syncthreads();

#pragma unroll
  for (int p = 0; p < 2; ++p) {
    const int n = (tid >> 3) + p * 32;
    const int kc = (tid & 7) * 8;
    union { u16 h[8]; uint4 v; } pk;
#pragma unroll
    for (int j = 0; j < 8; ++j) pk.h[j] = f2bf(t[kc + j][n]);
    *(uint4*)&Bt[(long)(n0 + n) * NN + k0 + kc] = pk.v;
  }
}

// ---------------------------------------------------------------------------
// Pass 2: R15 gemm (proven: lean 1-barrier step, phase-pipelined lgkmcnt(4),
// fine-interleaved staging, T2 swizzle, bf16 slabs) + 120 ZERO-FILL TAIL
// ITEMS (blocks >= nitems) that zero the strictly-upper 256x256 C tiles in
// the gemm's latency bubbles (dispatched last -> picked up by freeing CUs,
// off the 16-step critical path).
// ---------------------------------------------------------------------------
__global__ __launch_bounds__(512, 2) void gemm_tril(
    const u16* __restrict__ Ab, const u16* __restrict__ Bt,
    float* __restrict__ C, u16* __restrict__ P, int lg, int nitems) {
  extern __shared__ u16 lds[];  // [2][16384] A | [2][16384] B = 128 KB
  u16* AsB = lds;
  u16* BsB = lds + 32768;

  const int tid = threadIdx.x;

  if ((int)blockIdx.x >= nitems) {  // ---- zero a strictly-upper 256-tile ----
    int zi = blockIdx.x - nitems;   // 0..119
    int bi = 0;
    for (; bi < 15; ++bi) {
      const int u = 15 - bi;
      if (zi < u) break;
      zi -= u;
    }
    const int bj = bi + 1 + zi;
    const float4 z = {0.f, 0.f, 0.f, 0.f};
#pragma unroll
    for (int p = 0; p < 32; ++p) {
      const int idx = p * 512 + tid;  // 16384 float4 in 256x256 tile
      const int row = idx >> 6;
      const int col = (idx & 63) * 4;
      *(float4*)&C[(long)(bi * 256 + row) * NN + bj * 256 + col] = z;
    }
    return;
  }

  const int lane = tid & 63;
  const int wid = tid >> 6;  // 0..7
  const int wm = wid >> 2;   // 0..1 (128-row half)
  const int wn = wid & 3;    // 0..3 (64-col block)
  const int sm = lane >> 3;
  const int sks = ((lane & 7) ^ sm) * 8;  // pre-swizzled source col (u16)
  const int rsel = lane & 7;

  // ---- decode blockIdx.x -> (bi, bj, chunk); 256-rows longest-K-first ----
  int rem = blockIdx.x, bi = 15, slabpre = 0;
  for (int s = 0; s < 16; ++s) {
    bi = 15 - s;
    const int fp = Fpre(bi + 1, lg);
    const int g = (bi + 1) + fp;
    if (rem < g) break;
    rem -= g;
    slabpre += fp;
  }
  int bj = 0;
  for (;;) {
    const int c = ((bi - bj) >> lg) + 1;  // chunks of tile (bi,bj)
    if (rem < c) break;
    rem -= c;
    ++bj;
  }
  const int chunk = rem;
  const int L64 = 4 * (bi - bj + 1);
  const int H64 = 4 << lg;
  const int start = chunk * H64;
  const int nk = min(H64, L64 - start);
  const int rA = bi * 256;
  const int rB = bj * 256;
  const long kbase = (long)bj * 256 + (long)start * 64;

  f32x4 acc[8][4];
#pragma unroll
  for (int i = 0; i < 8; ++i)
#pragma unroll
    for (int j = 0; j < 4; ++j) acc[i][j] = (f32x4){0.f, 0.f, 0.f, 0.f};

  // stage part c (of 4) of K64-step kt into buffer b: 2 gload_lds16
#define STAGE_PART(kt, b, c)                                               \
  do {                                                                     \
    const long k0 = kbase + (long)(kt)*64;                                 \
    const int ch = wid * 4 + (c);                                          \
    gload_lds16(Ab + ((long)(rA + ch * 8 + sm) * NN + k0 + sks),           \
                AsB + (b)*16384 + ch * 512);                               \
    gload_lds16(Bt + ((long)(rB + ch * 8 + sm) * NN + k0 + sks),           \
                BsB + (b)*16384 + ch * 512);                               \
  } while (0)

#pragma unroll
  for (int c = 0; c < 4; ++c) STAGE_PART(0, 0, c);

  for (int kt = 0; kt < nk; ++kt) {
    const int cur = kt & 1;
    asm volatile("s_waitcnt vmcnt(0)" ::: "memory");  // own stage landed
    __builtin_amdgcn_s_barrier();                     // all waves' stage done
    __builtin_amdgcn_sched_barrier(0);                // no read hoists above

    const u16* As = AsB + cur * 16384;
    const u16* Bs = BsB + cur * 16384;
    const bool pf = (kt + 1 < nk);

    // B fragments (whole step) + A fragments for phase 0
    bf16x8 bb[4][2];
#pragma unroll
    for (int n4 = 0; n4 < 4; ++n4)
#pragma unroll
      for (int kk = 0; kk < 2; ++kk) {
        const int fr = wn * 64 + n4 * 16 + (lane & 15);
        const int slot = ((kk * 4 + (lane >> 4)) ^ rsel) * 8;
        bb[n4][kk] = *(const bf16x8*)&Bs[fr * 64 + slot];
      }
    bf16x8 aa[2][2][2];  // [phase&1][mm][kk]
#pragma unroll
    for (int mm = 0; mm < 2; ++mm)
#pragma unroll
      for (int kk = 0; kk < 2; ++kk) {
        const int fr = wm * 128 + mm * 16 + (lane & 15);
        const int slot = ((kk * 4 + (lane >> 4)) ^ rsel) * 8;
        aa[0][mm][kk] = *(const bf16x8*)&As[fr * 64 + slot];
      }

#pragma unroll
    for (int p = 0; p < 4; ++p) {
      if (pf) STAGE_PART(kt + 1, cur ^ 1, p);  // 2 global loads interleaved
      if (p < 3) {  // prefetch next phase's A fragments
#pragma unroll
        for (int mm = 0; mm < 2; ++mm)
#pragma unroll
          for (int kk = 0; kk < 2; ++kk) {
            const int fr = wm * 128 + (2 * (p + 1) + mm) * 16 + (lane & 15);
            const int slot = ((kk * 4 + (lane >> 4)) ^ rsel) * 8;
            aa[(p + 1) & 1][mm][kk] = *(const bf16x8*)&As[fr * 64 + slot];
          }
        asm volatile("s_waitcnt lgkmcnt(4)" ::: "memory");  // cur frags done
      } else {
        asm volatile("s_waitcnt lgkmcnt(0)" ::: "memory");
      }
      __builtin_amdgcn_sched_barrier(0);  // rule #18: no MFMA hoist past wait
      __builtin_amdgcn_s_setprio(1);
#pragma unroll
      for (int kk = 0; kk < 2; ++kk)
#pragma unroll
        for (int mm = 0; mm < 2; ++mm)
#pragma unroll
          for (int n4 = 0; n4 < 4; ++n4)
            acc[2 * p + mm][n4] = __builtin_amdgcn_mfma_f32_16x16x32_bf16(
                aa[p & 1][mm][kk], bb[n4][kk], acc[2 * p + mm][n4], 0, 0, 0);
      __builtin_amdgcn_s_setprio(0);
    }
  }
#undef STAGE_PART

  // ---- epilogue: C/D layout col=lane&15, row=(lane>>4)*4+r ----
  const int lrow = wm * 128 + (lane >> 4) * 4;
  const int lcol = wn * 64 + (lane & 15);
  if (chunk == 0) {
    const bool diag = (bi == bj);
#pragma unroll
    for (int m4 = 0; m4 < 8; ++m4)
#pragma unroll
      for (int n4 = 0; n4 < 4; ++n4)
#pragma unroll
        for (int r = 0; r < 4; ++r) {
          const int gi = rA + lrow + m4 * 16 + r;
          const int gj = rB + lcol + n4 * 16;
          float v = acc[m4][n4][r];
          if (diag && gj > gi) v = 0.f;
          C[(long)gi * NN + gj] = v;
        }
  } else {
    const int slabidx =
        slabpre + (Fpre(bi + 1, lg) - Fpre(bi - bj + 1, lg)) + (chunk - 1);
    u16* slab = P + (long)slabidx * 65536;  // 256x256 bf16 = 128 KB
#pragma unroll
    for (int m4 = 0; m4 < 8; ++m4)
#pragma unroll
      for (int n4 = 0; n4 < 4; ++n4)
#pragma unroll
        for (int r = 0; r < 4; ++r)
          slab[(lrow + m4 * 16 + r) * 256 + lcol + n4 * 16] =
              f2bf(acc[m4][n4][r]);
  }
}

// ---------------------------------------------------------------------------
// Pass 3: add bf16 partial slabs into C. Multi-chunk tiles only
// (bi-bj >= 2^lg), 4 row-stripes per tile.
// ---------------------------------------------------------------------------
__global__ __launch_bounds__(256) void reduce_partials(
    float* __restrict__ C, const u16* __restrict__ P, int lg) {
  const int G = 1 << lg;
  const int tb = blockIdx.x >> 2;
  const int stripe = blockIdx.x & 3;
  int rem = tb, bi = 15, slabpre = 0;
  for (int s = 0; s < 16; ++s) {
    bi = 15 - s;
    const int g = (bi + 1 - G > 0) ? bi + 1 - G : 0;
    if (rem < g) break;
    rem -= g;
    slabpre += Fpre(bi + 1, lg);
  }
  const int bj = rem;  // bj <= bi-G -> nch >= 2
  const int nch = ((bi - bj) >> lg) + 1;
  const int slaboff = slabpre + (Fpre(bi + 1, lg) - Fpre(bi - bj + 1, lg));

  const int tid = threadIdx.x;
#pragma unroll
  for (int p = 0; p < 16; ++p) {
    const int idx = p * 256 + tid;  // 4096 float4 per 64-row stripe
    const int row = stripe * 64 + (idx >> 6);
    const int col = (idx & 63) * 4;
    const long coff = (long)(bi * 256 + row) * NN + bj * 256 + col;
    float4 acc = *(const float4*)&C[coff];
    for (int e = 0; e < nch - 1; ++e) {
      const ushort4 q =
          *(const ushort4*)&P[(long)(slaboff + e) * 65536 + row * 256 + col];
      acc.x += bf2f(q.x); acc.y += bf2f(q.y);
      acc.z += bf2f(q.z); acc.w += bf2f(q.w);
    }
    *(float4*)&C[coff] = acc;
  }
}

// ---------------------------------------------------------------------------
// Fallback (ws too small): naive fp32.
// ---------------------------------------------------------------------------
__global__ void naive_tril(const float* __restrict__ A,
                           const float* __restrict__ B, float* __restrict__ C) {
  const int j = blockIdx.x * 256 + threadIdx.x;
  const int i = blockIdx.y;
  float s = 0.f;
  for (int k = j; k <= i; ++k) s += A[(long)i * NN + k] * B[(long)k * NN + j];
  C[(long)i * NN + j] = s;
}

extern "C" void kernel_launch(void* const* d_in, const int* in_sizes, int n_in,
                              void* d_out, int out_size, void* d_ws,
                              size_t ws_size, hipStream_t stream) {
  const float* A = (const float*)d_in[0];
  const float* B = (const float*)d_in[1];
  float* C = (float*)d_out;

  const size_t opbytes = (size_t)2 * NN * NN * sizeof(u16);  // 64 MB operands
  const size_t slab = 131072;  // 256x256 bf16
  // tiers (chunk = 4<<lg K64-steps): lg=2 (K=1024) proven best
  const size_t need2 = opbytes + 124 * slab;  // 79.5 MB
  const size_t need3 = opbytes + 36 * slab;

  if (ws_size < opbytes) {
    naive_tril<<<dim3(16, NN), 256, 0, stream>>>(A, B, C);
    return;
  }

  int lg, nitems, nred;
  if (ws_size >= need2)      { lg = 2; nitems = 260; nred = 78; }
  else if (ws_size >= need3) { lg = 3; nitems = 172; nred = 36; }
  else                       { lg = 4; nitems = 136; nred = 0; }

  u16* Ab = (u16*)d_ws;
  u16* Bt = Ab + (long)NN * NN;
  u16* P = (u16*)((char*)d_ws + opbytes);

  hipFuncSetAttribute((const void*)gemm_tril,
                      hipFuncAttributeMaxDynamicSharedMemorySize, 131072);

  convert_fused<<<3200, 256, 0, stream>>>(A, B, Ab, Bt);
  gemm_tril<<<nitems + 120, 512, 131072, stream>>>(Ab, Bt, C, P, lg, nitems);
  if (nred > 0) reduce_partials<<<nred * 4, 256, 0, stream>>>(C, P, lg);
}